// Round 17
// baseline (387.445 us; speedup 1.0000x reference)
//
#include <hip/hip_runtime.h>
#include <math.h>

#define NPIX 4096
#define CHSZ 3145728   // one num partial: 24*32*4096 floats
#define NRMSZ 98304    // one nrm partial: 24*4096 floats

// ---------------------------------------------------------------------------
// DPP-based 64-lane inclusive scan (VALU only, no LDS traffic)
// ---------------------------------------------------------------------------
template <int CTRL, int RM>
__device__ __forceinline__ float dpp_add(float x) {
    int xi = __builtin_bit_cast(int, x);
    int sh = __builtin_amdgcn_update_dpp(0, xi, CTRL, RM, 0xf, false);
    return x + __builtin_bit_cast(float, sh);
}

__device__ __forceinline__ float wave_iscan(float x) {
    x = dpp_add<0x111, 0xf>(x);   // row_shr:1
    x = dpp_add<0x112, 0xf>(x);   // row_shr:2
    x = dpp_add<0x114, 0xf>(x);   // row_shr:4
    x = dpp_add<0x118, 0xf>(x);   // row_shr:8
    x = dpp_add<0x142, 0xa>(x);   // row_bcast:15 -> rows 1,3
    x = dpp_add<0x143, 0xc>(x);   // row_bcast:31 -> rows 2,3
    return x;
}

// LDS-only barrier: drain lgkm (ds ops) but leave global loads in flight.
__device__ __forceinline__ void lds_barrier() {
    asm volatile("s_waitcnt lgkmcnt(0)" ::: "memory");
    __builtin_amdgcn_s_barrier();
    __builtin_amdgcn_sched_barrier(0);
}

// ---------------------------------------------------------------------------
// Kernel 1: fused QKV 1x1-conv GEMM, 128px x 32out tiles + register prefetch
// (frozen since R7).
// ---------------------------------------------------------------------------
__global__ __launch_bounds__(256) void qkv_kernel(
    const float* __restrict__ x, const float* __restrict__ Wq,
    const float* __restrict__ Wk, const float* __restrict__ Wv,
    float* __restrict__ qo, float* __restrict__ ko, float* __restrict__ vo)
{
    const int pt = blockIdx.x * 128;
    const int ot = blockIdx.y * 32;
    const int mat = blockIdx.z;
    const float* __restrict__ W = (mat == 0) ? Wq : ((mat == 1) ? Wk : Wv);
    float* __restrict__ out = (mat == 0) ? qo : ((mat == 1) ? ko : vo);

    __shared__ __align__(16) float Xs[32][132];
    __shared__ __align__(16) float Wt[32][36];   // [c][o]

    const int t = threadIdx.x;
    const int pc = t & 31;
    const int oc = t >> 5;
    const int xc = t >> 5;
    const int xp = (t & 31) << 2;
    const int lo = t >> 3;
    const int lg = (t & 7) << 2;

    float4 xf[4];
    float4 wf;
#pragma unroll
    for (int i = 0; i < 4; i++)
        xf[i] = *reinterpret_cast<const float4*>(x + (xc + 8 * i) * NPIX + pt + xp);
    wf = *reinterpret_cast<const float4*>(W + (ot + lo) * 256 + lg);

    float acc[4][4];
#pragma unroll
    for (int j = 0; j < 4; j++)
#pragma unroll
        for (int i = 0; i < 4; i++) acc[j][i] = 0.f;

    for (int kt = 0; kt < 256; kt += 32) {
#pragma unroll
        for (int i = 0; i < 4; i++)
            *reinterpret_cast<float4*>(&Xs[xc + 8 * i][xp]) = xf[i];
        Wt[lg + 0][lo] = wf.x;
        Wt[lg + 1][lo] = wf.y;
        Wt[lg + 2][lo] = wf.z;
        Wt[lg + 3][lo] = wf.w;
        __syncthreads();
        if (kt + 32 < 256) {
#pragma unroll
            for (int i = 0; i < 4; i++)
                xf[i] = *reinterpret_cast<const float4*>(
                    x + (kt + 32 + xc + 8 * i) * NPIX + pt + xp);
            wf = *reinterpret_cast<const float4*>(W + (ot + lo) * 256 + kt + 32 + lg);
        }
#pragma unroll
        for (int kk = 0; kk < 32; kk++) {
            float4 a = *reinterpret_cast<const float4*>(&Xs[kk][pc << 2]);
            float av[4] = {a.x, a.y, a.z, a.w};
            float4 b4 = *reinterpret_cast<const float4*>(&Wt[kk][oc << 2]);
            float bv[4] = {b4.x, b4.y, b4.z, b4.w};
#pragma unroll
            for (int j = 0; j < 4; j++)
#pragma unroll
                for (int i = 0; i < 4; i++)
                    acc[j][i] = fmaf(bv[j], av[i], acc[j][i]);
        }
        __syncthreads();
    }

    if (mat < 2) {
#pragma unroll
        for (int j = 0; j < 4; j++) {
            const int o = ot + (oc << 2) + j;
            float4 r;
            r.x = 1.f / (1.f + __expf(-acc[j][0]));
            r.y = 1.f / (1.f + __expf(-acc[j][1]));
            r.z = 1.f / (1.f + __expf(-acc[j][2]));
            r.w = 1.f / (1.f + __expf(-acc[j][3]));
            *reinterpret_cast<float4*>(out + o * NPIX + pt + (pc << 2)) = r;
        }
    } else {
        float* scratch = &Xs[0][0];
        __syncthreads();
#pragma unroll
        for (int i = 0; i < 4; i++) {
            float ss = 0.f;
#pragma unroll
            for (int j = 0; j < 4; j++) ss += acc[j][i] * acc[j][i];
            scratch[oc * 128 + (pc << 2) + i] = ss;
        }
        __syncthreads();
        float scale[4];
#pragma unroll
        for (int i = 0; i < 4; i++) {
            float tot = 0.f;
#pragma unroll
            for (int g = 0; g < 8; g++) tot += scratch[g * 128 + (pc << 2) + i];
            scale[i] = 1.f / fmaxf(sqrtf(tot), 1e-12f);
        }
#pragma unroll
        for (int j = 0; j < 4; j++) {
            const int o = ot + (oc << 2) + j;
            float4 r;
            r.x = acc[j][0] * scale[0];
            r.y = acc[j][1] * scale[1];
            r.z = acc[j][2] * scale[2];
            r.w = acc[j][3] * scale[3];
            *reinterpret_cast<float4*>(out + o * NPIX + pt + (pc << 2)) = r;
        }
    }
}

// ---------------------------------------------------------------------------
// Kernel 2: fused integral-image + windowed contraction, 512 threads (8 waves).
// R17: R9 structure (five-times-reproduced at 71.5-72.0 us) with the VGPR
// count pushed under the 64-register occupancy cliff (m69: waves/SIMD = 8 at
// <=64, 4 at 65-128 — we sat at 72 for six rounds = half residency):
//  - kcur[] / qv[] register prefetches removed (loads inline where consumed;
//    live set ~52-60 regs). TLP from doubled residency covers the latency
//    the prefetches used to hide.
//  - __launch_bounds__(512, 8) pins 8 waves/SIMD (allocator budget 64).
//    UNLIKE R2 (forced 64 with ~90 live -> mass spills), live fits here.
// LDS 36.9 KB -> 4 blocks/CU when VGPR-eligible. Barriers/layout unchanged.
// ---------------------------------------------------------------------------
template <int PD>
__global__ __launch_bounds__(512, 8) void attn_kernel(
    const float* __restrict__ q, const float* __restrict__ k,
    const float* __restrict__ v, float* __restrict__ num, float* __restrict__ nrm)
{
    const int f = blockIdx.x;          // 0..32 (32 == norm slot)
    const int head = blockIdx.y;       // 0..7
    const int dg = blockIdx.z;         // 0..(32/PD - 1)
    const bool isnorm = (f == 32);

    const float* __restrict__ kh = k + (head * 32 + dg * PD) * NPIX;
    const float* __restrict__ qh = q + (head * 32 + dg * PD) * NPIX;
    const float* __restrict__ vf = v + (head * 32 + (isnorm ? 0 : f)) * NPIX;

    __shared__ __align__(16) float Pt[65][132];   // 34,320 B
    __shared__ float csum[8][68];

    const int t = threadIdx.x;
    const int lane = t & 63;
    const int wv = t >> 6;             // 0..7

    for (int i = t; i < 65 * 132; i += 512) (&Pt[0][0])[i] = 0.f;

    float vreg[8];
#pragma unroll
    for (int i = 0; i < 8; i++)
        vreg[i] = isnorm ? 1.f : vf[(wv * 8 + i) * 64 + lane];

    float acc[3][8];
#pragma unroll
    for (int w = 0; w < 3; w++)
#pragma unroll
        for (int i = 0; i < 8; i++) acc[w][i] = 0.f;

    lds_barrier();                     // zero-init visible

    for (int dd = 0; dd < PD; dd++) {
        // phase 1: k loaded inline, row iscans + in-register EXCLUSIVE prefix
        float pv[8];
        float run = 0.f;
#pragma unroll
        for (int i = 0; i < 8; i++) {
            const float kv = kh[dd * NPIX + (wv * 8 + i) * 64 + lane];
            float rs = wave_iscan(kv * vreg[i]);
            pv[i] = run;               // P row (8*wv + i)
            run += rs;
        }
        csum[wv][lane] = run;
        lds_barrier();                 // A: csum ready; fences prev phase-4
        float off = 0.f;
#pragma unroll
        for (int w2 = 0; w2 < 7; w2++) if (w2 < wv) off += csum[w2][lane];
#pragma unroll
        for (int i = 0; i < 8; i++) pv[i] += off;
#pragma unroll
        for (int s = 0; s < 2; s++) {
            float4 r4 = make_float4(pv[4 * s], pv[4 * s + 1], pv[4 * s + 2], pv[4 * s + 3]);
            *reinterpret_cast<float4*>(&Pt[lane + 1][32 + wv * 8 + 4 * s]) = r4;
        }
        if (wv == 7) {                 // row y=64 (yp 96) + replicate pad
            const float tot = off + run;
            const float4 p4 = make_float4(tot, tot, tot, tot);
#pragma unroll
            for (int s = 0; s < 8; s++)
                *reinterpret_cast<float4*>(&Pt[lane + 1][96 + 4 * s]) = p4;
        }
        lds_barrier();                 // B: P complete
        // phase 4: q loaded inline, windowed box-diff contraction
#pragma unroll
        for (int g = 0; g < 2; g++) {
            const int y0 = (wv + 8 * g) * 4;
            float qv[4];
#pragma unroll
            for (int j = 0; j < 4; j++)
                qv[j] = qh[dd * NPIX + (y0 + j) * 64 + lane];
#pragma unroll
            for (int w = 0; w < 3; w++) {
                const int hw = 32 >> w;
                const int xlo = max(lane - hw, 0);
                const int xhi = min(lane + hw, 64);
                const int ylo = 32 + y0 - hw;
                const int yhi = 32 + y0 + hw;
                float4 A4 = *reinterpret_cast<const float4*>(&Pt[xhi][yhi]);
                float4 B4 = *reinterpret_cast<const float4*>(&Pt[xlo][yhi]);
                float4 C4, E4;
                if (y0 + 3 <= hw) {    // wave-uniform: whole quad in zero pad
                    C4 = make_float4(0.f, 0.f, 0.f, 0.f);
                    E4 = C4;
                } else {
                    C4 = *reinterpret_cast<const float4*>(&Pt[xhi][ylo]);
                    E4 = *reinterpret_cast<const float4*>(&Pt[xlo][ylo]);
                }
                acc[w][g * 4 + 0] = fmaf(qv[0], (A4.x - B4.x) - (C4.x - E4.x), acc[w][g * 4 + 0]);
                acc[w][g * 4 + 1] = fmaf(qv[1], (A4.y - B4.y) - (C4.y - E4.y), acc[w][g * 4 + 1]);
                acc[w][g * 4 + 2] = fmaf(qv[2], (A4.z - B4.z) - (C4.z - E4.z), acc[w][g * 4 + 2]);
                acc[w][g * 4 + 3] = fmaf(qv[3], (A4.w - B4.w) - (C4.w - E4.w), acc[w][g * 4 + 3]);
            }
        }
        // no trailing barrier: next iter's barrier A fences Pt rewrite
    }

    float* __restrict__ nout = num + (size_t)dg * CHSZ;
    float* __restrict__ rout = nrm + (size_t)dg * NRMSZ;
#pragma unroll
    for (int w = 0; w < 3; w++) {
#pragma unroll
        for (int g = 0; g < 2; g++) {
#pragma unroll
            for (int j = 0; j < 4; j++) {
                const int px = ((wv + 8 * g) * 4 + j) * 64 + lane;
                const float val = acc[w][g * 4 + j];
                if (isnorm) rout[(w * 8 + head) * NPIX + px] = val;
                else        nout[((w * 8 + head) * 32 + f) * NPIX + px] = val;
            }
        }
    }
}

// ---------------------------------------------------------------------------
// Kernel 3: final 1x1 conv partial; R11-EXACT (measured floor config):
// 64px x 64out, acc[4][4], 256 thr, K-split 2, grid (64, 4, 2).
// ---------------------------------------------------------------------------
template <int NS>
__global__ __launch_bounds__(256) void out_kernel(
    const float* __restrict__ num, const float* __restrict__ nrm,
    const float* __restrict__ Wout, float* __restrict__ obuf)
{
    const int pt = blockIdx.x * 64;
    const int ot = blockIdx.y * 64;
    const int kt0 = blockIdx.z * 12;
    __shared__ __align__(16) float As[32][68];
    __shared__ __align__(16) float Wt[32][68];   // [c][o]
    const int t = threadIdx.x;
    const int pc = t & 15;
    const int oc = t >> 4;
    const int xc = t >> 4;
    const int xp = (t & 15) << 2;
    const int lo = t & 63;
    const int lc = (t >> 6) << 2;

    float4 nv[NS][2], mv[NS], wf[2];
#pragma unroll
    for (int s = 0; s < NS; s++) {
#pragma unroll
        for (int i = 0; i < 2; i++)
            nv[s][i] = *reinterpret_cast<const float4*>(
                num + (size_t)s * CHSZ + (size_t)(kt0 * 32 + xc + 16 * i) * NPIX + pt + xp);
        mv[s] = *reinterpret_cast<const float4*>(
            nrm + (size_t)s * NRMSZ + kt0 * NPIX + pt + xp);
    }
    wf[0] = *reinterpret_cast<const float4*>(Wout + (ot + lo) * 768 + kt0 * 32 + lc);
    wf[1] = *reinterpret_cast<const float4*>(Wout + (ot + lo) * 768 + kt0 * 32 + lc + 16);

    float acc[4][4];
#pragma unroll
    for (int j = 0; j < 4; j++)
#pragma unroll
        for (int i = 0; i < 4; i++) acc[j][i] = 0.f;

    for (int kt = kt0; kt < kt0 + 12; kt++) {
        float4 ms = mv[0];
#pragma unroll
        for (int s = 1; s < NS; s++) {
            ms.x += mv[s].x; ms.y += mv[s].y; ms.z += mv[s].z; ms.w += mv[s].w;
        }
        float4 rv;
        rv.x = 1.f / (ms.x + 1e-6f); rv.y = 1.f / (ms.y + 1e-6f);
        rv.z = 1.f / (ms.z + 1e-6f); rv.w = 1.f / (ms.w + 1e-6f);
#pragma unroll
        for (int i = 0; i < 2; i++) {
            float4 r = nv[0][i];
#pragma unroll
            for (int s = 1; s < NS; s++) {
                r.x += nv[s][i].x; r.y += nv[s][i].y;
                r.z += nv[s][i].z; r.w += nv[s][i].w;
            }
            r.x *= rv.x; r.y *= rv.y; r.z *= rv.z; r.w *= rv.w;
            *reinterpret_cast<float4*>(&As[xc + 16 * i][xp]) = r;
        }
#pragma unroll
        for (int i = 0; i < 2; i++) {
            Wt[lc + 16 * i + 0][lo] = wf[i].x;
            Wt[lc + 16 * i + 1][lo] = wf[i].y;
            Wt[lc + 16 * i + 2][lo] = wf[i].z;
            Wt[lc + 16 * i + 3][lo] = wf[i].w;
        }
        __syncthreads();
        if (kt + 1 < kt0 + 12) {
#pragma unroll
            for (int s = 0; s < NS; s++) {
#pragma unroll
                for (int i = 0; i < 2; i++)
                    nv[s][i] = *reinterpret_cast<const float4*>(
                        num + (size_t)s * CHSZ +
                        (size_t)((kt + 1) * 32 + xc + 16 * i) * NPIX + pt + xp);
                mv[s] = *reinterpret_cast<const float4*>(
                    nrm + (size_t)s * NRMSZ + (kt + 1) * NPIX + pt + xp);
            }
            wf[0] = *reinterpret_cast<const float4*>(
                Wout + (ot + lo) * 768 + (kt + 1) * 32 + lc);
            wf[1] = *reinterpret_cast<const float4*>(
                Wout + (ot + lo) * 768 + (kt + 1) * 32 + lc + 16);
        }
#pragma unroll
        for (int kk = 0; kk < 32; kk++) {
            float4 a = *reinterpret_cast<const float4*>(&As[kk][pc << 2]);
            float av[4] = {a.x, a.y, a.z, a.w};
            float4 b4 = *reinterpret_cast<const float4*>(&Wt[kk][oc << 2]);
            float bv[4] = {b4.x, b4.y, b4.z, b4.w};
#pragma unroll
            for (int j = 0; j < 4; j++)
#pragma unroll
                for (int i = 0; i < 4; i++)
                    acc[j][i] = fmaf(bv[j], av[i], acc[j][i]);
        }
        __syncthreads();
    }

    float* __restrict__ ob = obuf + (size_t)blockIdx.z * 1048576;
#pragma unroll
    for (int j = 0; j < 4; j++) {
        const int o = ot + (oc << 2) + j;
        float4 r;
        r.x = acc[j][0]; r.y = acc[j][1]; r.z = acc[j][2]; r.w = acc[j][3];
        *reinterpret_cast<float4*>(ob + o * NPIX + pt + (pc << 2)) = r;
    }
}

// ---------------------------------------------------------------------------
// Kernel 4: merge 2 K-split partials + bias. 1M floats, float4/thread.
// ---------------------------------------------------------------------------
__global__ __launch_bounds__(256) void kmerge_kernel(
    const float* __restrict__ obuf, const float* __restrict__ bout,
    float* __restrict__ out)
{
    const int i4 = (blockIdx.x * 256 + threadIdx.x) * 4;
    const float bb = bout[i4 >> 12];
    float4 a = *reinterpret_cast<const float4*>(obuf + i4);
    float4 b = *reinterpret_cast<const float4*>(obuf + 1048576 + i4);
    float4 r;
    r.x = a.x + b.x + bb;
    r.y = a.y + b.y + bb;
    r.z = a.z + b.z + bb;
    r.w = a.w + b.w + bb;
    *reinterpret_cast<float4*>(out + i4) = r;
}

extern "C" void kernel_launch(void* const* d_in, const int* in_sizes, int n_in,
                              void* d_out, int out_size, void* d_ws, size_t ws_size,
                              hipStream_t stream)
{
    const float* x    = (const float*)d_in[0];
    const float* Wq   = (const float*)d_in[1];
    const float* Wk   = (const float*)d_in[2];
    const float* Wv   = (const float*)d_in[3];
    const float* Wout = (const float*)d_in[4];
    const float* bout = (const float*)d_in[5];
    float* out = (float*)d_out;

    float* ws = (float*)d_ws;
    float* q   = ws;                  // 1,048,576 floats
    float* k   = ws + 1048576;
    float* v   = ws + 2097152;
    float* num = ws + 3145728;        // NS partials of CHSZ, then NS of NRMSZ
    float* obuf = ws;                 // 2 x 1M — aliases dead q/k
    const size_t fl = ws_size / 4;

    qkv_kernel<<<dim3(32, 8, 3), 256, 0, stream>>>(x, Wq, Wk, Wv, q, k, v);

    if (fl >= 3145728 + (size_t)4 * (CHSZ + NRMSZ)) {        // NS = 4
        float* nrm = num + (size_t)4 * CHSZ;
        attn_kernel<8><<<dim3(33, 8, 4), 512, 0, stream>>>(q, k, v, num, nrm);
        out_kernel<4><<<dim3(64, 4, 2), 256, 0, stream>>>(num, nrm, Wout, obuf);
    } else if (fl >= 3145728 + (size_t)2 * (CHSZ + NRMSZ)) { // NS = 2
        float* nrm = num + (size_t)2 * CHSZ;
        attn_kernel<16><<<dim3(33, 8, 2), 512, 0, stream>>>(q, k, v, num, nrm);
        out_kernel<2><<<dim3(64, 4, 2), 256, 0, stream>>>(num, nrm, Wout, obuf);
    } else {                                                 // NS = 1
        float* nrm = num + CHSZ;
        attn_kernel<32><<<dim3(33, 8, 1), 512, 0, stream>>>(q, k, v, num, nrm);
        out_kernel<1><<<dim3(64, 4, 2), 256, 0, stream>>>(num, nrm, Wout, obuf);
    }
    kmerge_kernel<<<dim3(1024), 256, 0, stream>>>(obuf, bout, out);
}

// Round 18
// 126.106 us; speedup vs baseline: 3.0724x; 3.0724x over previous
//
#include <hip/hip_runtime.h>
#include <math.h>

#define NPIX 4096
#define CHSZ 3145728   // one num partial: 24*32*4096 floats
#define NRMSZ 98304    // one nrm partial: 24*4096 floats

// ---------------------------------------------------------------------------
// DPP-based 64-lane inclusive scan (VALU only, no LDS traffic)
// ---------------------------------------------------------------------------
template <int CTRL, int RM>
__device__ __forceinline__ float dpp_add(float x) {
    int xi = __builtin_bit_cast(int, x);
    int sh = __builtin_amdgcn_update_dpp(0, xi, CTRL, RM, 0xf, false);
    return x + __builtin_bit_cast(float, sh);
}

__device__ __forceinline__ float wave_iscan(float x) {
    x = dpp_add<0x111, 0xf>(x);   // row_shr:1
    x = dpp_add<0x112, 0xf>(x);   // row_shr:2
    x = dpp_add<0x114, 0xf>(x);   // row_shr:4
    x = dpp_add<0x118, 0xf>(x);   // row_shr:8
    x = dpp_add<0x142, 0xa>(x);   // row_bcast:15 -> rows 1,3
    x = dpp_add<0x143, 0xc>(x);   // row_bcast:31 -> rows 2,3
    return x;
}

// LDS-only barrier: drain lgkm (ds ops) but leave global loads in flight.
__device__ __forceinline__ void lds_barrier() {
    asm volatile("s_waitcnt lgkmcnt(0)" ::: "memory");
    __builtin_amdgcn_s_barrier();
    __builtin_amdgcn_sched_barrier(0);
}

// ---------------------------------------------------------------------------
// Kernel 1: fused QKV 1x1-conv GEMM, 128px x 32out tiles + register prefetch
// (frozen since R7).
// ---------------------------------------------------------------------------
__global__ __launch_bounds__(256) void qkv_kernel(
    const float* __restrict__ x, const float* __restrict__ Wq,
    const float* __restrict__ Wk, const float* __restrict__ Wv,
    float* __restrict__ qo, float* __restrict__ ko, float* __restrict__ vo)
{
    const int pt = blockIdx.x * 128;
    const int ot = blockIdx.y * 32;
    const int mat = blockIdx.z;
    const float* __restrict__ W = (mat == 0) ? Wq : ((mat == 1) ? Wk : Wv);
    float* __restrict__ out = (mat == 0) ? qo : ((mat == 1) ? ko : vo);

    __shared__ __align__(16) float Xs[32][132];
    __shared__ __align__(16) float Wt[32][36];   // [c][o]

    const int t = threadIdx.x;
    const int pc = t & 31;
    const int oc = t >> 5;
    const int xc = t >> 5;
    const int xp = (t & 31) << 2;
    const int lo = t >> 3;
    const int lg = (t & 7) << 2;

    float4 xf[4];
    float4 wf;
#pragma unroll
    for (int i = 0; i < 4; i++)
        xf[i] = *reinterpret_cast<const float4*>(x + (xc + 8 * i) * NPIX + pt + xp);
    wf = *reinterpret_cast<const float4*>(W + (ot + lo) * 256 + lg);

    float acc[4][4];
#pragma unroll
    for (int j = 0; j < 4; j++)
#pragma unroll
        for (int i = 0; i < 4; i++) acc[j][i] = 0.f;

    for (int kt = 0; kt < 256; kt += 32) {
#pragma unroll
        for (int i = 0; i < 4; i++)
            *reinterpret_cast<float4*>(&Xs[xc + 8 * i][xp]) = xf[i];
        Wt[lg + 0][lo] = wf.x;
        Wt[lg + 1][lo] = wf.y;
        Wt[lg + 2][lo] = wf.z;
        Wt[lg + 3][lo] = wf.w;
        __syncthreads();
        if (kt + 32 < 256) {
#pragma unroll
            for (int i = 0; i < 4; i++)
                xf[i] = *reinterpret_cast<const float4*>(
                    x + (kt + 32 + xc + 8 * i) * NPIX + pt + xp);
            wf = *reinterpret_cast<const float4*>(W + (ot + lo) * 256 + kt + 32 + lg);
        }
#pragma unroll
        for (int kk = 0; kk < 32; kk++) {
            float4 a = *reinterpret_cast<const float4*>(&Xs[kk][pc << 2]);
            float av[4] = {a.x, a.y, a.z, a.w};
            float4 b4 = *reinterpret_cast<const float4*>(&Wt[kk][oc << 2]);
            float bv[4] = {b4.x, b4.y, b4.z, b4.w};
#pragma unroll
            for (int j = 0; j < 4; j++)
#pragma unroll
                for (int i = 0; i < 4; i++)
                    acc[j][i] = fmaf(bv[j], av[i], acc[j][i]);
        }
        __syncthreads();
    }

    if (mat < 2) {
#pragma unroll
        for (int j = 0; j < 4; j++) {
            const int o = ot + (oc << 2) + j;
            float4 r;
            r.x = 1.f / (1.f + __expf(-acc[j][0]));
            r.y = 1.f / (1.f + __expf(-acc[j][1]));
            r.z = 1.f / (1.f + __expf(-acc[j][2]));
            r.w = 1.f / (1.f + __expf(-acc[j][3]));
            *reinterpret_cast<float4*>(out + o * NPIX + pt + (pc << 2)) = r;
        }
    } else {
        float* scratch = &Xs[0][0];
        __syncthreads();
#pragma unroll
        for (int i = 0; i < 4; i++) {
            float ss = 0.f;
#pragma unroll
            for (int j = 0; j < 4; j++) ss += acc[j][i] * acc[j][i];
            scratch[oc * 128 + (pc << 2) + i] = ss;
        }
        __syncthreads();
        float scale[4];
#pragma unroll
        for (int i = 0; i < 4; i++) {
            float tot = 0.f;
#pragma unroll
            for (int g = 0; g < 8; g++) tot += scratch[g * 128 + (pc << 2) + i];
            scale[i] = 1.f / fmaxf(sqrtf(tot), 1e-12f);
        }
#pragma unroll
        for (int j = 0; j < 4; j++) {
            const int o = ot + (oc << 2) + j;
            float4 r;
            r.x = acc[j][0] * scale[0];
            r.y = acc[j][1] * scale[1];
            r.z = acc[j][2] * scale[2];
            r.w = acc[j][3] * scale[3];
            *reinterpret_cast<float4*>(out + o * NPIX + pt + (pc << 2)) = r;
        }
    }
}

// ---------------------------------------------------------------------------
// Kernel 2: fused integral-image + windowed contraction, 512 threads (8 waves).
// R18: R9 structure, inline k/q loads (no prefetch regs, live ~52-60), with
// launch hint recalibrated from R17's measurement:
//   (512,8) -> VGPR 32 (budget ~256/arg) -> spill disaster (535MB scratch).
//   (512,4) -> predicted VGPR budget 64 = exactly the m69 occupancy cliff;
//   live set fits -> no spills, 8 waves/SIMD, 4 blocks/CU (LDS 36.9KB ok).
// Spill tripwire: WRITE_SIZE must stay ~50688 KB; if ballooned, revert R16.
// ---------------------------------------------------------------------------
template <int PD>
__global__ __launch_bounds__(512, 4) void attn_kernel(
    const float* __restrict__ q, const float* __restrict__ k,
    const float* __restrict__ v, float* __restrict__ num, float* __restrict__ nrm)
{
    const int f = blockIdx.x;          // 0..32 (32 == norm slot)
    const int head = blockIdx.y;       // 0..7
    const int dg = blockIdx.z;         // 0..(32/PD - 1)
    const bool isnorm = (f == 32);

    const float* __restrict__ kh = k + (head * 32 + dg * PD) * NPIX;
    const float* __restrict__ qh = q + (head * 32 + dg * PD) * NPIX;
    const float* __restrict__ vf = v + (head * 32 + (isnorm ? 0 : f)) * NPIX;

    __shared__ __align__(16) float Pt[65][132];   // 34,320 B
    __shared__ float csum[8][68];

    const int t = threadIdx.x;
    const int lane = t & 63;
    const int wv = t >> 6;             // 0..7

    for (int i = t; i < 65 * 132; i += 512) (&Pt[0][0])[i] = 0.f;

    float vreg[8];
#pragma unroll
    for (int i = 0; i < 8; i++)
        vreg[i] = isnorm ? 1.f : vf[(wv * 8 + i) * 64 + lane];

    float acc[3][8];
#pragma unroll
    for (int w = 0; w < 3; w++)
#pragma unroll
        for (int i = 0; i < 8; i++) acc[w][i] = 0.f;

    lds_barrier();                     // zero-init visible

    for (int dd = 0; dd < PD; dd++) {
        // phase 1: k loaded inline, row iscans + in-register EXCLUSIVE prefix
        float pv[8];
        float run = 0.f;
#pragma unroll
        for (int i = 0; i < 8; i++) {
            const float kv = kh[dd * NPIX + (wv * 8 + i) * 64 + lane];
            float rs = wave_iscan(kv * vreg[i]);
            pv[i] = run;               // P row (8*wv + i)
            run += rs;
        }
        csum[wv][lane] = run;
        lds_barrier();                 // A: csum ready; fences prev phase-4
        float off = 0.f;
#pragma unroll
        for (int w2 = 0; w2 < 7; w2++) if (w2 < wv) off += csum[w2][lane];
#pragma unroll
        for (int i = 0; i < 8; i++) pv[i] += off;
#pragma unroll
        for (int s = 0; s < 2; s++) {
            float4 r4 = make_float4(pv[4 * s], pv[4 * s + 1], pv[4 * s + 2], pv[4 * s + 3]);
            *reinterpret_cast<float4*>(&Pt[lane + 1][32 + wv * 8 + 4 * s]) = r4;
        }
        if (wv == 7) {                 // row y=64 (yp 96) + replicate pad
            const float tot = off + run;
            const float4 p4 = make_float4(tot, tot, tot, tot);
#pragma unroll
            for (int s = 0; s < 8; s++)
                *reinterpret_cast<float4*>(&Pt[lane + 1][96 + 4 * s]) = p4;
        }
        lds_barrier();                 // B: P complete
        // phase 4: q loaded inline, windowed box-diff contraction
#pragma unroll
        for (int g = 0; g < 2; g++) {
            const int y0 = (wv + 8 * g) * 4;
            float qv[4];
#pragma unroll
            for (int j = 0; j < 4; j++)
                qv[j] = qh[dd * NPIX + (y0 + j) * 64 + lane];
#pragma unroll
            for (int w = 0; w < 3; w++) {
                const int hw = 32 >> w;
                const int xlo = max(lane - hw, 0);
                const int xhi = min(lane + hw, 64);
                const int ylo = 32 + y0 - hw;
                const int yhi = 32 + y0 + hw;
                float4 A4 = *reinterpret_cast<const float4*>(&Pt[xhi][yhi]);
                float4 B4 = *reinterpret_cast<const float4*>(&Pt[xlo][yhi]);
                float4 C4, E4;
                if (y0 + 3 <= hw) {    // wave-uniform: whole quad in zero pad
                    C4 = make_float4(0.f, 0.f, 0.f, 0.f);
                    E4 = C4;
                } else {
                    C4 = *reinterpret_cast<const float4*>(&Pt[xhi][ylo]);
                    E4 = *reinterpret_cast<const float4*>(&Pt[xlo][ylo]);
                }
                acc[w][g * 4 + 0] = fmaf(qv[0], (A4.x - B4.x) - (C4.x - E4.x), acc[w][g * 4 + 0]);
                acc[w][g * 4 + 1] = fmaf(qv[1], (A4.y - B4.y) - (C4.y - E4.y), acc[w][g * 4 + 1]);
                acc[w][g * 4 + 2] = fmaf(qv[2], (A4.z - B4.z) - (C4.z - E4.z), acc[w][g * 4 + 2]);
                acc[w][g * 4 + 3] = fmaf(qv[3], (A4.w - B4.w) - (C4.w - E4.w), acc[w][g * 4 + 3]);
            }
        }
        // no trailing barrier: next iter's barrier A fences Pt rewrite
    }

    float* __restrict__ nout = num + (size_t)dg * CHSZ;
    float* __restrict__ rout = nrm + (size_t)dg * NRMSZ;
#pragma unroll
    for (int w = 0; w < 3; w++) {
#pragma unroll
        for (int g = 0; g < 2; g++) {
#pragma unroll
            for (int j = 0; j < 4; j++) {
                const int px = ((wv + 8 * g) * 4 + j) * 64 + lane;
                const float val = acc[w][g * 4 + j];
                if (isnorm) rout[(w * 8 + head) * NPIX + px] = val;
                else        nout[((w * 8 + head) * 32 + f) * NPIX + px] = val;
            }
        }
    }
}

// ---------------------------------------------------------------------------
// Kernel 3: final 1x1 conv partial; R11-EXACT (measured floor config):
// 64px x 64out, acc[4][4], 256 thr, K-split 2, grid (64, 4, 2).
// ---------------------------------------------------------------------------
template <int NS>
__global__ __launch_bounds__(256) void out_kernel(
    const float* __restrict__ num, const float* __restrict__ nrm,
    const float* __restrict__ Wout, float* __restrict__ obuf)
{
    const int pt = blockIdx.x * 64;
    const int ot = blockIdx.y * 64;
    const int kt0 = blockIdx.z * 12;
    __shared__ __align__(16) float As[32][68];
    __shared__ __align__(16) float Wt[32][68];   // [c][o]
    const int t = threadIdx.x;
    const int pc = t & 15;
    const int oc = t >> 4;
    const int xc = t >> 4;
    const int xp = (t & 15) << 2;
    const int lo = t & 63;
    const int lc = (t >> 6) << 2;

    float4 nv[NS][2], mv[NS], wf[2];
#pragma unroll
    for (int s = 0; s < NS; s++) {
#pragma unroll
        for (int i = 0; i < 2; i++)
            nv[s][i] = *reinterpret_cast<const float4*>(
                num + (size_t)s * CHSZ + (size_t)(kt0 * 32 + xc + 16 * i) * NPIX + pt + xp);
        mv[s] = *reinterpret_cast<const float4*>(
            nrm + (size_t)s * NRMSZ + kt0 * NPIX + pt + xp);
    }
    wf[0] = *reinterpret_cast<const float4*>(Wout + (ot + lo) * 768 + kt0 * 32 + lc);
    wf[1] = *reinterpret_cast<const float4*>(Wout + (ot + lo) * 768 + kt0 * 32 + lc + 16);

    float acc[4][4];
#pragma unroll
    for (int j = 0; j < 4; j++)
#pragma unroll
        for (int i = 0; i < 4; i++) acc[j][i] = 0.f;

    for (int kt = kt0; kt < kt0 + 12; kt++) {
        float4 ms = mv[0];
#pragma unroll
        for (int s = 1; s < NS; s++) {
            ms.x += mv[s].x; ms.y += mv[s].y; ms.z += mv[s].z; ms.w += mv[s].w;
        }
        float4 rv;
        rv.x = 1.f / (ms.x + 1e-6f); rv.y = 1.f / (ms.y + 1e-6f);
        rv.z = 1.f / (ms.z + 1e-6f); rv.w = 1.f / (ms.w + 1e-6f);
#pragma unroll
        for (int i = 0; i < 2; i++) {
            float4 r = nv[0][i];
#pragma unroll
            for (int s = 1; s < NS; s++) {
                r.x += nv[s][i].x; r.y += nv[s][i].y;
                r.z += nv[s][i].z; r.w += nv[s][i].w;
            }
            r.x *= rv.x; r.y *= rv.y; r.z *= rv.z; r.w *= rv.w;
            *reinterpret_cast<float4*>(&As[xc + 16 * i][xp]) = r;
        }
#pragma unroll
        for (int i = 0; i < 2; i++) {
            Wt[lc + 16 * i + 0][lo] = wf[i].x;
            Wt[lc + 16 * i + 1][lo] = wf[i].y;
            Wt[lc + 16 * i + 2][lo] = wf[i].z;
            Wt[lc + 16 * i + 3][lo] = wf[i].w;
        }
        __syncthreads();
        if (kt + 1 < kt0 + 12) {
#pragma unroll
            for (int s = 0; s < NS; s++) {
#pragma unroll
                for (int i = 0; i < 2; i++)
                    nv[s][i] = *reinterpret_cast<const float4*>(
                        num + (size_t)s * CHSZ +
                        (size_t)((kt + 1) * 32 + xc + 16 * i) * NPIX + pt + xp);
                mv[s] = *reinterpret_cast<const float4*>(
                    nrm + (size_t)s * NRMSZ + (kt + 1) * NPIX + pt + xp);
            }
            wf[0] = *reinterpret_cast<const float4*>(
                Wout + (ot + lo) * 768 + (kt + 1) * 32 + lc);
            wf[1] = *reinterpret_cast<const float4*>(
                Wout + (ot + lo) * 768 + (kt + 1) * 32 + lc + 16);
        }
#pragma unroll
        for (int kk = 0; kk < 32; kk++) {
            float4 a = *reinterpret_cast<const float4*>(&As[kk][pc << 2]);
            float av[4] = {a.x, a.y, a.z, a.w};
            float4 b4 = *reinterpret_cast<const float4*>(&Wt[kk][oc << 2]);
            float bv[4] = {b4.x, b4.y, b4.z, b4.w};
#pragma unroll
            for (int j = 0; j < 4; j++)
#pragma unroll
                for (int i = 0; i < 4; i++)
                    acc[j][i] = fmaf(bv[j], av[i], acc[j][i]);
        }
        __syncthreads();
    }

    float* __restrict__ ob = obuf + (size_t)blockIdx.z * 1048576;
#pragma unroll
    for (int j = 0; j < 4; j++) {
        const int o = ot + (oc << 2) + j;
        float4 r;
        r.x = acc[j][0]; r.y = acc[j][1]; r.z = acc[j][2]; r.w = acc[j][3];
        *reinterpret_cast<float4*>(ob + o * NPIX + pt + (pc << 2)) = r;
    }
}

// ---------------------------------------------------------------------------
// Kernel 4: merge 2 K-split partials + bias. 1M floats, float4/thread.
// ---------------------------------------------------------------------------
__global__ __launch_bounds__(256) void kmerge_kernel(
    const float* __restrict__ obuf, const float* __restrict__ bout,
    float* __restrict__ out)
{
    const int i4 = (blockIdx.x * 256 + threadIdx.x) * 4;
    const float bb = bout[i4 >> 12];
    float4 a = *reinterpret_cast<const float4*>(obuf + i4);
    float4 b = *reinterpret_cast<const float4*>(obuf + 1048576 + i4);
    float4 r;
    r.x = a.x + b.x + bb;
    r.y = a.y + b.y + bb;
    r.z = a.z + b.z + bb;
    r.w = a.w + b.w + bb;
    *reinterpret_cast<float4*>(out + i4) = r;
}

extern "C" void kernel_launch(void* const* d_in, const int* in_sizes, int n_in,
                              void* d_out, int out_size, void* d_ws, size_t ws_size,
                              hipStream_t stream)
{
    const float* x    = (const float*)d_in[0];
    const float* Wq   = (const float*)d_in[1];
    const float* Wk   = (const float*)d_in[2];
    const float* Wv   = (const float*)d_in[3];
    const float* Wout = (const float*)d_in[4];
    const float* bout = (const float*)d_in[5];
    float* out = (float*)d_out;

    float* ws = (float*)d_ws;
    float* q   = ws;                  // 1,048,576 floats
    float* k   = ws + 1048576;
    float* v   = ws + 2097152;
    float* num = ws + 3145728;        // NS partials of CHSZ, then NS of NRMSZ
    float* obuf = ws;                 // 2 x 1M — aliases dead q/k
    const size_t fl = ws_size / 4;

    qkv_kernel<<<dim3(32, 8, 3), 256, 0, stream>>>(x, Wq, Wk, Wv, q, k, v);

    if (fl >= 3145728 + (size_t)4 * (CHSZ + NRMSZ)) {        // NS = 4
        float* nrm = num + (size_t)4 * CHSZ;
        attn_kernel<8><<<dim3(33, 8, 4), 512, 0, stream>>>(q, k, v, num, nrm);
        out_kernel<4><<<dim3(64, 4, 2), 256, 0, stream>>>(num, nrm, Wout, obuf);
    } else if (fl >= 3145728 + (size_t)2 * (CHSZ + NRMSZ)) { // NS = 2
        float* nrm = num + (size_t)2 * CHSZ;
        attn_kernel<16><<<dim3(33, 8, 2), 512, 0, stream>>>(q, k, v, num, nrm);
        out_kernel<2><<<dim3(64, 4, 2), 256, 0, stream>>>(num, nrm, Wout, obuf);
    } else {                                                 // NS = 1
        float* nrm = num + CHSZ;
        attn_kernel<32><<<dim3(33, 8, 1), 512, 0, stream>>>(q, k, v, num, nrm);
        out_kernel<1><<<dim3(64, 4, 2), 256, 0, stream>>>(num, nrm, Wout, obuf);
    }
    kmerge_kernel<<<dim3(1024), 256, 0, stream>>>(obuf, bout, out);
}

// Round 19
// 124.005 us; speedup vs baseline: 3.1244x; 1.0169x over previous
//
#include <hip/hip_runtime.h>
#include <math.h>

#define NPIX 4096
#define CHSZ 3145728   // one num partial: 24*32*4096 floats
#define NRMSZ 98304    // one nrm partial: 24*4096 floats

// ---------------------------------------------------------------------------
// DPP-based 64-lane inclusive scan (VALU only, no LDS traffic)
// ---------------------------------------------------------------------------
template <int CTRL, int RM>
__device__ __forceinline__ float dpp_add(float x) {
    int xi = __builtin_bit_cast(int, x);
    int sh = __builtin_amdgcn_update_dpp(0, xi, CTRL, RM, 0xf, false);
    return x + __builtin_bit_cast(float, sh);
}

__device__ __forceinline__ float wave_iscan(float x) {
    x = dpp_add<0x111, 0xf>(x);   // row_shr:1
    x = dpp_add<0x112, 0xf>(x);   // row_shr:2
    x = dpp_add<0x114, 0xf>(x);   // row_shr:4
    x = dpp_add<0x118, 0xf>(x);   // row_shr:8
    x = dpp_add<0x142, 0xa>(x);   // row_bcast:15 -> rows 1,3
    x = dpp_add<0x143, 0xc>(x);   // row_bcast:31 -> rows 2,3
    return x;
}

// LDS-only barrier: drain lgkm (ds ops) but leave global loads in flight.
__device__ __forceinline__ void lds_barrier() {
    asm volatile("s_waitcnt lgkmcnt(0)" ::: "memory");
    __builtin_amdgcn_s_barrier();
    __builtin_amdgcn_sched_barrier(0);
}

// ---------------------------------------------------------------------------
// Kernel 1: fused QKV 1x1-conv GEMM, 128px x 32out tiles + register prefetch
// (frozen since R7).
// ---------------------------------------------------------------------------
__global__ __launch_bounds__(256) void qkv_kernel(
    const float* __restrict__ x, const float* __restrict__ Wq,
    const float* __restrict__ Wk, const float* __restrict__ Wv,
    float* __restrict__ qo, float* __restrict__ ko, float* __restrict__ vo)
{
    const int pt = blockIdx.x * 128;
    const int ot = blockIdx.y * 32;
    const int mat = blockIdx.z;
    const float* __restrict__ W = (mat == 0) ? Wq : ((mat == 1) ? Wk : Wv);
    float* __restrict__ out = (mat == 0) ? qo : ((mat == 1) ? ko : vo);

    __shared__ __align__(16) float Xs[32][132];
    __shared__ __align__(16) float Wt[32][36];   // [c][o]

    const int t = threadIdx.x;
    const int pc = t & 31;
    const int oc = t >> 5;
    const int xc = t >> 5;
    const int xp = (t & 31) << 2;
    const int lo = t >> 3;
    const int lg = (t & 7) << 2;

    float4 xf[4];
    float4 wf;
#pragma unroll
    for (int i = 0; i < 4; i++)
        xf[i] = *reinterpret_cast<const float4*>(x + (xc + 8 * i) * NPIX + pt + xp);
    wf = *reinterpret_cast<const float4*>(W + (ot + lo) * 256 + lg);

    float acc[4][4];
#pragma unroll
    for (int j = 0; j < 4; j++)
#pragma unroll
        for (int i = 0; i < 4; i++) acc[j][i] = 0.f;

    for (int kt = 0; kt < 256; kt += 32) {
#pragma unroll
        for (int i = 0; i < 4; i++)
            *reinterpret_cast<float4*>(&Xs[xc + 8 * i][xp]) = xf[i];
        Wt[lg + 0][lo] = wf.x;
        Wt[lg + 1][lo] = wf.y;
        Wt[lg + 2][lo] = wf.z;
        Wt[lg + 3][lo] = wf.w;
        __syncthreads();
        if (kt + 32 < 256) {
#pragma unroll
            for (int i = 0; i < 4; i++)
                xf[i] = *reinterpret_cast<const float4*>(
                    x + (kt + 32 + xc + 8 * i) * NPIX + pt + xp);
            wf = *reinterpret_cast<const float4*>(W + (ot + lo) * 256 + kt + 32 + lg);
        }
#pragma unroll
        for (int kk = 0; kk < 32; kk++) {
            float4 a = *reinterpret_cast<const float4*>(&Xs[kk][pc << 2]);
            float av[4] = {a.x, a.y, a.z, a.w};
            float4 b4 = *reinterpret_cast<const float4*>(&Wt[kk][oc << 2]);
            float bv[4] = {b4.x, b4.y, b4.z, b4.w};
#pragma unroll
            for (int j = 0; j < 4; j++)
#pragma unroll
                for (int i = 0; i < 4; i++)
                    acc[j][i] = fmaf(bv[j], av[i], acc[j][i]);
        }
        __syncthreads();
    }

    if (mat < 2) {
#pragma unroll
        for (int j = 0; j < 4; j++) {
            const int o = ot + (oc << 2) + j;
            float4 r;
            r.x = 1.f / (1.f + __expf(-acc[j][0]));
            r.y = 1.f / (1.f + __expf(-acc[j][1]));
            r.z = 1.f / (1.f + __expf(-acc[j][2]));
            r.w = 1.f / (1.f + __expf(-acc[j][3]));
            *reinterpret_cast<float4*>(out + o * NPIX + pt + (pc << 2)) = r;
        }
    } else {
        float* scratch = &Xs[0][0];
        __syncthreads();
#pragma unroll
        for (int i = 0; i < 4; i++) {
            float ss = 0.f;
#pragma unroll
            for (int j = 0; j < 4; j++) ss += acc[j][i] * acc[j][i];
            scratch[oc * 128 + (pc << 2) + i] = ss;
        }
        __syncthreads();
        float scale[4];
#pragma unroll
        for (int i = 0; i < 4; i++) {
            float tot = 0.f;
#pragma unroll
            for (int g = 0; g < 8; g++) tot += scratch[g * 128 + (pc << 2) + i];
            scale[i] = 1.f / fmaxf(sqrtf(tot), 1e-12f);
        }
#pragma unroll
        for (int j = 0; j < 4; j++) {
            const int o = ot + (oc << 2) + j;
            float4 r;
            r.x = acc[j][0] * scale[0];
            r.y = acc[j][1] * scale[1];
            r.z = acc[j][2] * scale[2];
            r.w = acc[j][3] * scale[3];
            *reinterpret_cast<float4*>(out + o * NPIX + pt + (pc << 2)) = r;
        }
    }
}

// ---------------------------------------------------------------------------
// Kernel 2: fused integral-image + windowed contraction, 512 threads (8 waves).
// R18-EXACT (measured 53.3 us, VGPR 64, occ 29%): R9 structure, inline k/q
// loads, __launch_bounds__(512,4) -> VGPR budget 64 (empirical: 256/arg).
// FROZEN — do not touch.
// ---------------------------------------------------------------------------
template <int PD>
__global__ __launch_bounds__(512, 4) void attn_kernel(
    const float* __restrict__ q, const float* __restrict__ k,
    const float* __restrict__ v, float* __restrict__ num, float* __restrict__ nrm)
{
    const int f = blockIdx.x;          // 0..32 (32 == norm slot)
    const int head = blockIdx.y;       // 0..7
    const int dg = blockIdx.z;         // 0..(32/PD - 1)
    const bool isnorm = (f == 32);

    const float* __restrict__ kh = k + (head * 32 + dg * PD) * NPIX;
    const float* __restrict__ qh = q + (head * 32 + dg * PD) * NPIX;
    const float* __restrict__ vf = v + (head * 32 + (isnorm ? 0 : f)) * NPIX;

    __shared__ __align__(16) float Pt[65][132];   // 34,320 B
    __shared__ float csum[8][68];

    const int t = threadIdx.x;
    const int lane = t & 63;
    const int wv = t >> 6;             // 0..7

    for (int i = t; i < 65 * 132; i += 512) (&Pt[0][0])[i] = 0.f;

    float vreg[8];
#pragma unroll
    for (int i = 0; i < 8; i++)
        vreg[i] = isnorm ? 1.f : vf[(wv * 8 + i) * 64 + lane];

    float acc[3][8];
#pragma unroll
    for (int w = 0; w < 3; w++)
#pragma unroll
        for (int i = 0; i < 8; i++) acc[w][i] = 0.f;

    lds_barrier();                     // zero-init visible

    for (int dd = 0; dd < PD; dd++) {
        // phase 1: k loaded inline, row iscans + in-register EXCLUSIVE prefix
        float pv[8];
        float run = 0.f;
#pragma unroll
        for (int i = 0; i < 8; i++) {
            const float kv = kh[dd * NPIX + (wv * 8 + i) * 64 + lane];
            float rs = wave_iscan(kv * vreg[i]);
            pv[i] = run;               // P row (8*wv + i)
            run += rs;
        }
        csum[wv][lane] = run;
        lds_barrier();                 // A: csum ready; fences prev phase-4
        float off = 0.f;
#pragma unroll
        for (int w2 = 0; w2 < 7; w2++) if (w2 < wv) off += csum[w2][lane];
#pragma unroll
        for (int i = 0; i < 8; i++) pv[i] += off;
#pragma unroll
        for (int s = 0; s < 2; s++) {
            float4 r4 = make_float4(pv[4 * s], pv[4 * s + 1], pv[4 * s + 2], pv[4 * s + 3]);
            *reinterpret_cast<float4*>(&Pt[lane + 1][32 + wv * 8 + 4 * s]) = r4;
        }
        if (wv == 7) {                 // row y=64 (yp 96) + replicate pad
            const float tot = off + run;
            const float4 p4 = make_float4(tot, tot, tot, tot);
#pragma unroll
            for (int s = 0; s < 8; s++)
                *reinterpret_cast<float4*>(&Pt[lane + 1][96 + 4 * s]) = p4;
        }
        lds_barrier();                 // B: P complete
        // phase 4: q loaded inline, windowed box-diff contraction
#pragma unroll
        for (int g = 0; g < 2; g++) {
            const int y0 = (wv + 8 * g) * 4;
            float qv[4];
#pragma unroll
            for (int j = 0; j < 4; j++)
                qv[j] = qh[dd * NPIX + (y0 + j) * 64 + lane];
#pragma unroll
            for (int w = 0; w < 3; w++) {
                const int hw = 32 >> w;
                const int xlo = max(lane - hw, 0);
                const int xhi = min(lane + hw, 64);
                const int ylo = 32 + y0 - hw;
                const int yhi = 32 + y0 + hw;
                float4 A4 = *reinterpret_cast<const float4*>(&Pt[xhi][yhi]);
                float4 B4 = *reinterpret_cast<const float4*>(&Pt[xlo][yhi]);
                float4 C4, E4;
                if (y0 + 3 <= hw) {    // wave-uniform: whole quad in zero pad
                    C4 = make_float4(0.f, 0.f, 0.f, 0.f);
                    E4 = C4;
                } else {
                    C4 = *reinterpret_cast<const float4*>(&Pt[xhi][ylo]);
                    E4 = *reinterpret_cast<const float4*>(&Pt[xlo][ylo]);
                }
                acc[w][g * 4 + 0] = fmaf(qv[0], (A4.x - B4.x) - (C4.x - E4.x), acc[w][g * 4 + 0]);
                acc[w][g * 4 + 1] = fmaf(qv[1], (A4.y - B4.y) - (C4.y - E4.y), acc[w][g * 4 + 1]);
                acc[w][g * 4 + 2] = fmaf(qv[2], (A4.z - B4.z) - (C4.z - E4.z), acc[w][g * 4 + 2]);
                acc[w][g * 4 + 3] = fmaf(qv[3], (A4.w - B4.w) - (C4.w - E4.w), acc[w][g * 4 + 3]);
            }
        }
        // no trailing barrier: next iter's barrier A fences Pt rewrite
    }

    float* __restrict__ nout = num + (size_t)dg * CHSZ;
    float* __restrict__ rout = nrm + (size_t)dg * NRMSZ;
#pragma unroll
    for (int w = 0; w < 3; w++) {
#pragma unroll
        for (int g = 0; g < 2; g++) {
#pragma unroll
            for (int j = 0; j < 4; j++) {
                const int px = ((wv + 8 * g) * 4 + j) * 64 + lane;
                const float val = acc[w][g * 4 + j];
                if (isnorm) rout[(w * 8 + head) * NPIX + px] = val;
                else        nout[((w * 8 + head) * 32 + f) * NPIX + px] = val;
            }
        }
    }
}

// ---------------------------------------------------------------------------
// Kernel 3a (primary): 128px x 64out, acc[8][4] (10.7 FMA/b128 vs 8 for
// acc[4][4] — out is LDS-THROUGHPUT-bound, R10-R15 evidence) at K-split 4:
// grid (32,4,4) = 512 blocks = exactly 2.0/CU (R14's 1.5/CU imbalance fixed).
// NS partials summed AT LOAD (snv — keeps VGPR ~85, no cliff).
// ---------------------------------------------------------------------------
template <int NS, int KS>
__global__ __launch_bounds__(256) void out128_kernel(
    const float* __restrict__ num, const float* __restrict__ nrm,
    const float* __restrict__ Wout, float* __restrict__ obufA,
    float* __restrict__ obufB)
{
    const int pt = blockIdx.x * 128;
    const int ot = blockIdx.y * 64;
    constexpr int KC = 24 / KS;
    const int kt0 = blockIdx.z * KC;
    __shared__ __align__(16) float As[32][132];
    __shared__ __align__(16) float Wt[32][68];   // [c][o]
    const int t = threadIdx.x;
    const int pc = t & 31;         // 32 pixel groups x 4 px
    const int oc = t >> 5;         // 8 output groups x 8 o
    const int xc = t >> 5;         // staging c rows xc + 8*i
    const int xp = (t & 31) << 2;
    const int lo = t & 63;         // W loader: o
    const int lc = (t >> 6) << 2;  // W loader: c bases lc, lc+16

    float4 snv[4], smv, wf[2];
#pragma unroll
    for (int i = 0; i < 4; i++) {
        snv[i] = *reinterpret_cast<const float4*>(
            num + (size_t)(kt0 * 32 + xc + 8 * i) * NPIX + pt + xp);
#pragma unroll
        for (int s = 1; s < NS; s++) {
            float4 v2 = *reinterpret_cast<const float4*>(
                num + (size_t)s * CHSZ + (size_t)(kt0 * 32 + xc + 8 * i) * NPIX + pt + xp);
            snv[i].x += v2.x; snv[i].y += v2.y; snv[i].z += v2.z; snv[i].w += v2.w;
        }
    }
    smv = *reinterpret_cast<const float4*>(nrm + kt0 * NPIX + pt + xp);
#pragma unroll
    for (int s = 1; s < NS; s++) {
        float4 v2 = *reinterpret_cast<const float4*>(
            nrm + (size_t)s * NRMSZ + kt0 * NPIX + pt + xp);
        smv.x += v2.x; smv.y += v2.y; smv.z += v2.z; smv.w += v2.w;
    }
    wf[0] = *reinterpret_cast<const float4*>(Wout + (ot + lo) * 768 + kt0 * 32 + lc);
    wf[1] = *reinterpret_cast<const float4*>(Wout + (ot + lo) * 768 + kt0 * 32 + lc + 16);

    float acc[8][4];
#pragma unroll
    for (int j = 0; j < 8; j++)
#pragma unroll
        for (int i = 0; i < 4; i++) acc[j][i] = 0.f;

    for (int kt = kt0; kt < kt0 + KC; kt++) {
        float4 rv;
        rv.x = 1.f / (smv.x + 1e-6f); rv.y = 1.f / (smv.y + 1e-6f);
        rv.z = 1.f / (smv.z + 1e-6f); rv.w = 1.f / (smv.w + 1e-6f);
#pragma unroll
        for (int i = 0; i < 4; i++) {
            float4 r;
            r.x = snv[i].x * rv.x; r.y = snv[i].y * rv.y;
            r.z = snv[i].z * rv.z; r.w = snv[i].w * rv.w;
            *reinterpret_cast<float4*>(&As[xc + 8 * i][xp]) = r;
        }
#pragma unroll
        for (int i = 0; i < 2; i++) {
            Wt[lc + 16 * i + 0][lo] = wf[i].x;
            Wt[lc + 16 * i + 1][lo] = wf[i].y;
            Wt[lc + 16 * i + 2][lo] = wf[i].z;
            Wt[lc + 16 * i + 3][lo] = wf[i].w;
        }
        __syncthreads();
        if (kt + 1 < kt0 + KC) {       // prefetch next channel tile (summed)
#pragma unroll
            for (int i = 0; i < 4; i++) {
                snv[i] = *reinterpret_cast<const float4*>(
                    num + (size_t)((kt + 1) * 32 + xc + 8 * i) * NPIX + pt + xp);
#pragma unroll
                for (int s = 1; s < NS; s++) {
                    float4 v2 = *reinterpret_cast<const float4*>(
                        num + (size_t)s * CHSZ +
                        (size_t)((kt + 1) * 32 + xc + 8 * i) * NPIX + pt + xp);
                    snv[i].x += v2.x; snv[i].y += v2.y;
                    snv[i].z += v2.z; snv[i].w += v2.w;
                }
            }
            smv = *reinterpret_cast<const float4*>(
                nrm + (kt + 1) * NPIX + pt + xp);
#pragma unroll
            for (int s = 1; s < NS; s++) {
                float4 v2 = *reinterpret_cast<const float4*>(
                    nrm + (size_t)s * NRMSZ + (kt + 1) * NPIX + pt + xp);
                smv.x += v2.x; smv.y += v2.y; smv.z += v2.z; smv.w += v2.w;
            }
            wf[0] = *reinterpret_cast<const float4*>(
                Wout + (ot + lo) * 768 + (kt + 1) * 32 + lc);
            wf[1] = *reinterpret_cast<const float4*>(
                Wout + (ot + lo) * 768 + (kt + 1) * 32 + lc + 16);
        }
#pragma unroll
        for (int kk = 0; kk < 32; kk++) {
            float4 a = *reinterpret_cast<const float4*>(&As[kk][pc << 2]);
            float av[4] = {a.x, a.y, a.z, a.w};
            float4 b0 = *reinterpret_cast<const float4*>(&Wt[kk][oc << 3]);
            float4 b1 = *reinterpret_cast<const float4*>(&Wt[kk][(oc << 3) + 4]);
            float bv[8] = {b0.x, b0.y, b0.z, b0.w, b1.x, b1.y, b1.z, b1.w};
#pragma unroll
            for (int j = 0; j < 8; j++)
#pragma unroll
                for (int i = 0; i < 4; i++)
                    acc[j][i] = fmaf(bv[j], av[i], acc[j][i]);
        }
        __syncthreads();
    }

    float* __restrict__ ob = (blockIdx.z < 3)
        ? (obufA + (size_t)blockIdx.z * 1048576) : obufB;
#pragma unroll
    for (int j = 0; j < 8; j++) {
        const int o = ot + (oc << 3) + j;
        float4 r;
        r.x = acc[j][0]; r.y = acc[j][1]; r.z = acc[j][2]; r.w = acc[j][3];
        *reinterpret_cast<float4*>(ob + o * NPIX + pt + (pc << 2)) = r;
    }
}

// ---------------------------------------------------------------------------
// Kernel 3b (fallback): R11-exact 64x64 acc[4][4] KS=2 out.
// ---------------------------------------------------------------------------
template <int NS>
__global__ __launch_bounds__(256) void out64_kernel(
    const float* __restrict__ num, const float* __restrict__ nrm,
    const float* __restrict__ Wout, float* __restrict__ obuf)
{
    const int pt = blockIdx.x * 64;
    const int ot = blockIdx.y * 64;
    const int kt0 = blockIdx.z * 12;
    __shared__ __align__(16) float As[32][68];
    __shared__ __align__(16) float Wt[32][68];
    const int t = threadIdx.x;
    const int pc = t & 15;
    const int oc = t >> 4;
    const int xc = t >> 4;
    const int xp = (t & 15) << 2;
    const int lo = t & 63;
    const int lc = (t >> 6) << 2;

    float4 nv[NS][2], mv[NS], wf[2];
#pragma unroll
    for (int s = 0; s < NS; s++) {
#pragma unroll
        for (int i = 0; i < 2; i++)
            nv[s][i] = *reinterpret_cast<const float4*>(
                num + (size_t)s * CHSZ + (size_t)(kt0 * 32 + xc + 16 * i) * NPIX + pt + xp);
        mv[s] = *reinterpret_cast<const float4*>(
            nrm + (size_t)s * NRMSZ + kt0 * NPIX + pt + xp);
    }
    wf[0] = *reinterpret_cast<const float4*>(Wout + (ot + lo) * 768 + kt0 * 32 + lc);
    wf[1] = *reinterpret_cast<const float4*>(Wout + (ot + lo) * 768 + kt0 * 32 + lc + 16);

    float acc[4][4];
#pragma unroll
    for (int j = 0; j < 4; j++)
#pragma unroll
        for (int i = 0; i < 4; i++) acc[j][i] = 0.f;

    for (int kt = kt0; kt < kt0 + 12; kt++) {
        float4 ms = mv[0];
#pragma unroll
        for (int s = 1; s < NS; s++) {
            ms.x += mv[s].x; ms.y += mv[s].y; ms.z += mv[s].z; ms.w += mv[s].w;
        }
        float4 rv;
        rv.x = 1.f / (ms.x + 1e-6f); rv.y = 1.f / (ms.y + 1e-6f);
        rv.z = 1.f / (ms.z + 1e-6f); rv.w = 1.f / (ms.w + 1e-6f);
#pragma unroll
        for (int i = 0; i < 2; i++) {
            float4 r = nv[0][i];
#pragma unroll
            for (int s = 1; s < NS; s++) {
                r.x += nv[s][i].x; r.y += nv[s][i].y;
                r.z += nv[s][i].z; r.w += nv[s][i].w;
            }
            r.x *= rv.x; r.y *= rv.y; r.z *= rv.z; r.w *= rv.w;
            *reinterpret_cast<float4*>(&As[xc + 16 * i][xp]) = r;
        }
#pragma unroll
        for (int i = 0; i < 2; i++) {
            Wt[lc + 16 * i + 0][lo] = wf[i].x;
            Wt[lc + 16 * i + 1][lo] = wf[i].y;
            Wt[lc + 16 * i + 2][lo] = wf[i].z;
            Wt[lc + 16 * i + 3][lo] = wf[i].w;
        }
        __syncthreads();
        if (kt + 1 < kt0 + 12) {
#pragma unroll
            for (int s = 0; s < NS; s++) {
#pragma unroll
                for (int i = 0; i < 2; i++)
                    nv[s][i] = *reinterpret_cast<const float4*>(
                        num + (size_t)s * CHSZ +
                        (size_t)((kt + 1) * 32 + xc + 16 * i) * NPIX + pt + xp);
                mv[s] = *reinterpret_cast<const float4*>(
                    nrm + (size_t)s * NRMSZ + (kt + 1) * NPIX + pt + xp);
            }
            wf[0] = *reinterpret_cast<const float4*>(
                Wout + (ot + lo) * 768 + (kt + 1) * 32 + lc);
            wf[1] = *reinterpret_cast<const float4*>(
                Wout + (ot + lo) * 768 + (kt + 1) * 32 + lc + 16);
        }
#pragma unroll
        for (int kk = 0; kk < 32; kk++) {
            float4 a = *reinterpret_cast<const float4*>(&As[kk][pc << 2]);
            float av[4] = {a.x, a.y, a.z, a.w};
            float4 b4 = *reinterpret_cast<const float4*>(&Wt[kk][oc << 2]);
            float bv[4] = {b4.x, b4.y, b4.z, b4.w};
#pragma unroll
            for (int j = 0; j < 4; j++)
#pragma unroll
                for (int i = 0; i < 4; i++)
                    acc[j][i] = fmaf(bv[j], av[i], acc[j][i]);
        }
        __syncthreads();
    }

    float* __restrict__ ob = obuf + (size_t)blockIdx.z * 1048576;
#pragma unroll
    for (int j = 0; j < 4; j++) {
        const int o = ot + (oc << 2) + j;
        float4 r;
        r.x = acc[j][0]; r.y = acc[j][1]; r.z = acc[j][2]; r.w = acc[j][3];
        *reinterpret_cast<float4*>(ob + o * NPIX + pt + (pc << 2)) = r;
    }
}

// ---------------------------------------------------------------------------
// Kernel 4: merge KS K-split partials + bias. 1M floats, float4/thread.
// ---------------------------------------------------------------------------
template <int KS>
__global__ __launch_bounds__(256) void kmerge_kernel(
    const float* __restrict__ obufA, const float* __restrict__ obufB,
    const float* __restrict__ bout, float* __restrict__ out)
{
    const int i4 = (blockIdx.x * 256 + threadIdx.x) * 4;
    const float bb = bout[i4 >> 12];
    float4 a = *reinterpret_cast<const float4*>(obufA + i4);
    float4 b = *reinterpret_cast<const float4*>(obufA + 1048576 + i4);
    float rx = a.x + b.x, ry = a.y + b.y, rz = a.z + b.z, rw = a.w + b.w;
    if (KS == 4) {
        float4 c = *reinterpret_cast<const float4*>(obufA + 2097152 + i4);
        float4 d = *reinterpret_cast<const float4*>(obufB + i4);
        rx += c.x + d.x; ry += c.y + d.y; rz += c.z + d.z; rw += c.w + d.w;
    }
    float4 r = make_float4(rx + bb, ry + bb, rz + bb, rw + bb);
    *reinterpret_cast<float4*>(out + i4) = r;
}

extern "C" void kernel_launch(void* const* d_in, const int* in_sizes, int n_in,
                              void* d_out, int out_size, void* d_ws, size_t ws_size,
                              hipStream_t stream)
{
    const float* x    = (const float*)d_in[0];
    const float* Wq   = (const float*)d_in[1];
    const float* Wk   = (const float*)d_in[2];
    const float* Wv   = (const float*)d_in[3];
    const float* Wout = (const float*)d_in[4];
    const float* bout = (const float*)d_in[5];
    float* out = (float*)d_out;

    float* ws = (float*)d_ws;
    float* q   = ws;                  // 1,048,576 floats
    float* k   = ws + 1048576;
    float* v   = ws + 2097152;
    float* num = ws + 3145728;        // NS partials of CHSZ, then NS of NRMSZ
    float* obufA = ws;                // 3 x 1M — aliases dead q/k/v
    const size_t fl = ws_size / 4;

    const size_t need_ns4 = 3145728 + (size_t)4 * (CHSZ + NRMSZ);   // 16121856
    const size_t need_ks4 = need_ns4 + 1048576;                      // 17170432

    qkv_kernel<<<dim3(32, 8, 3), 256, 0, stream>>>(x, Wq, Wk, Wv, q, k, v);

    if (fl >= need_ks4) {                    // NS = 4, KS = 4 (primary)
        float* nrm = num + (size_t)4 * CHSZ;
        float* obufB = ws + need_ns4;        // workspace tail, 1M floats
        attn_kernel<8><<<dim3(33, 8, 4), 512, 0, stream>>>(q, k, v, num, nrm);
        out128_kernel<4, 4><<<dim3(32, 4, 4), 256, 0, stream>>>(num, nrm, Wout, obufA, obufB);
        kmerge_kernel<4><<<dim3(1024), 256, 0, stream>>>(obufA, obufB, bout, out);
    } else if (fl >= need_ns4) {             // NS = 4, KS = 2 fallback
        float* nrm = num + (size_t)4 * CHSZ;
        attn_kernel<8><<<dim3(33, 8, 4), 512, 0, stream>>>(q, k, v, num, nrm);
        out64_kernel<4><<<dim3(64, 4, 2), 256, 0, stream>>>(num, nrm, Wout, obufA);
        kmerge_kernel<2><<<dim3(1024), 256, 0, stream>>>(obufA, obufA, bout, out);
    } else if (fl >= 3145728 + (size_t)2 * (CHSZ + NRMSZ)) {  // NS = 2
        float* nrm = num + (size_t)2 * CHSZ;
        attn_kernel<16><<<dim3(33, 8, 2), 512, 0, stream>>>(q, k, v, num, nrm);
        out64_kernel<2><<<dim3(64, 4, 2), 256, 0, stream>>>(num, nrm, Wout, obufA);
        kmerge_kernel<2><<<dim3(1024), 256, 0, stream>>>(obufA, obufA, bout, out);
    } else {                                 // NS = 1
        float* nrm = num + CHSZ;
        attn_kernel<32><<<dim3(33, 8, 1), 512, 0, stream>>>(q, k, v, num, nrm);
        out64_kernel<1><<<dim3(64, 4, 2), 256, 0, stream>>>(num, nrm, Wout, obufA);
        kmerge_kernel<2><<<dim3(1024), 256, 0, stream>>>(obufA, obufA, bout, out);
    }
}